// Round 5
// baseline (41496.802 us; speedup 1.0000x reference)
//
#include <hip/hip_runtime.h>
#include <cstdint>
#include <cstddef>

#define B_ 256
#define S_ 512

typedef _Float16 f16;
typedef _Float16 f16x8 __attribute__((ext_vector_type(8)));
typedef float f32x4 __attribute__((ext_vector_type(4)));
using u32 = unsigned int;
using u16 = unsigned short;

__device__ __forceinline__ float sigf(float x) { return 1.f / (1.f + __expf(-x)); }
__device__ __forceinline__ float tanh_f(float x) {
  x = fminf(15.f, fmaxf(-15.f, x));
  const float e = __expf(-2.f * x);
  return (1.f - e) / (1.f + e);
}
__device__ __forceinline__ f16x8 cvt_f16x8(float4 a, float4 b) {
  f16x8 t;
  t[0] = (f16)a.x; t[1] = (f16)a.y; t[2] = (f16)a.z; t[3] = (f16)a.w;
  t[4] = (f16)b.x; t[5] = (f16)b.y; t[6] = (f16)b.z; t[7] = (f16)b.w;
  return t;
}

// ---------------------------------------------------------------------------
// Persistent fused BiLSTM layer, ONE plain launch per layer (256 wgs = 1/CU).
// logical wg = dir*128 + bg*8 + sl : 16 batch rows x 128 gate cols.
// W_ih (f16) and W_hh (f16 hi + f16 lo*2^10) slices live in registers.
// gates = x@Wih^T + h@WhhHi^T + (h@WhhLo^T)/1024 + b  via mfma 16x16x32 f16.
// h exchanged through hout (f16, packed u32) with agent-scope atomics +
// per-(dir,bg) 8-wg counter barrier (ctr in d_out, re-zeroed every launch).
// x-MFMAs for step s+1 issue BETWEEN ctr-post and spin (latency overlap).
// ---------------------------------------------------------------------------
template<typename TIN, int KIN>
__global__ __launch_bounds__(256, 1) void lstm_layer(
    const TIN* __restrict__ xin,    // [B][S][KIN]  (x fp32 or prev hbuf f16)
    const float* __restrict__ w_ih, // [2][1024][KIN]
    const float* __restrict__ w_hh, // [2][1024][256]
    const float* __restrict__ bias, // [2][1024]
    f16* __restrict__ hout,         // [B][S][512]
    u32* __restrict__ ctr)          // [32] zeroed counters for this layer
{
  constexpr int GPR = KIN / 8;                  // 8-f16 granules per input row
  __shared__ __align__(16) f16 x_s[16 * KIN];
  __shared__ __align__(16) f16 h_s[16 * 256];
  __shared__ float gates_s[64 * 33];

  const int tid = threadIdx.x;
  const int lane = tid & 63, w = tid >> 6;
  const int l15 = lane & 15, l4 = lane >> 4;
  const int phys = blockIdx.x;
  const int wg = ((phys & 7) << 5) | (phys >> 3);  // co-locate groups per XCD
  const int dir = wg >> 7, bg = (wg >> 3) & 15, sl = wg & 7;
  const int grp = (dir << 4) | bg;

  // ---- weight slices -> registers ----
  f16x8 bih[2][KIN / 32];
  f16x8 bhhH[2][8], bhhL[2][8];
#pragma unroll
  for (int nt = 0; nt < 2; ++nt) {
    const int grow = (w << 8) + (sl << 5) + (nt << 4) + l15;   // gate col
    const float* pih = w_ih + ((size_t)(dir << 10) + grow) * KIN + (l4 << 3);
#pragma unroll
    for (int kt = 0; kt < KIN / 32; ++kt) {
      const float* p = pih + (kt << 5);
      bih[nt][kt] = cvt_f16x8(*(const float4*)p, *(const float4*)(p + 4));
    }
    const float* phh = w_hh + ((size_t)(dir << 10) + grow) * 256 + (l4 << 3);
#pragma unroll
    for (int kt = 0; kt < 8; ++kt) {
      const float* p = phh + (kt << 5);
      float wf[8];
      *(float4*)&wf[0] = *(const float4*)p;
      *(float4*)&wf[4] = *(const float4*)(p + 4);
      f16x8 hi, lo;
#pragma unroll
      for (int j = 0; j < 8; ++j) {
        hi[j] = (f16)wf[j];
        lo[j] = (f16)((wf[j] - (float)hi[j]) * 1024.f);
      }
      bhhH[nt][kt] = hi;
      bhhL[nt][kt] = lo;
    }
  }

  // ---- per-thread cell constants ----
  const int crow = tid >> 4;
  const int u0 = (tid & 15) << 1;
  float bv[4][2];
#pragma unroll
  for (int g = 0; g < 4; ++g)
#pragma unroll
    for (int j = 0; j < 2; ++j)
      bv[g][j] = bias[(dir << 10) + (g << 8) + (sl << 5) + u0 + j];
  float cs0 = 0.f, cs1 = 0.f;

  // ---------- staging helpers (inline blocks) ----------
#define STAGE_X(T_OR)                                                          \
  {                                                                            \
    constexpr int NG = 16 * GPR;                                               \
    _Pragma("unroll")                                                          \
    for (int i = 0; i < (NG + 255) / 256; ++i) {                               \
      const int G = tid + (i << 8);                                            \
      if (NG < 256 && G >= NG) break;                                          \
      const int row = G / GPR, g = G % GPR;                                    \
      const int b = (bg << 4) + row;                                           \
      f16x8 v;                                                                 \
      if constexpr (sizeof(TIN) == 4) {                                        \
        const float* p = (const float*)xin + ((size_t)b * S_ + (T_OR)) * KIN + (g << 3); \
        v = cvt_f16x8(*(const float4*)p, *(const float4*)(p + 4));             \
      } else {                                                                 \
        v = *(const f16x8*)((const f16*)xin + ((size_t)b * S_ + (T_OR)) * KIN + (g << 3)); \
      }                                                                        \
      *(f16x8*)&x_s[row * KIN + ((g ^ (row & 7)) << 3)] = v;                   \
    }                                                                          \
  }

#define X_MFMA(A0, A1)                                                         \
  {                                                                            \
    _Pragma("unroll")                                                          \
    for (int kt = 0; kt < KIN / 32; ++kt) {                                    \
      const int g = ((kt << 2) + l4) ^ (l15 & 7);                              \
      const f16x8 a = *(const f16x8*)&x_s[l15 * KIN + (g << 3)];               \
      A0 = __builtin_amdgcn_mfma_f32_16x16x32_f16(a, bih[0][kt], A0, 0, 0, 0); \
      A1 = __builtin_amdgcn_mfma_f32_16x16x32_f16(a, bih[1][kt], A1, 0, 0, 0); \
    }                                                                          \
  }

  // ---- prologue: stage x(0), compute its x-part ----
  const int t_or0 = dir ? (S_ - 1) : 0;
  STAGE_X(t_or0);
  __syncthreads();
  f32x4 accx0 = {}, accx1 = {};
  X_MFMA(accx0, accx1);

  for (int s = 0; s < S_; ++s) {
    const int t_or = dir ? (S_ - 1 - s) : s;

    // ---- stage h(s-1) (ready per barrier) ----
    if (s > 0) {
      const int t_pr = dir ? (t_or + 1) : (t_or - 1);
#pragma unroll
      for (int i = 0; i < 2; ++i) {
        const int G = tid + (i << 8);
        const int row = G >> 5, g = G & 31;
        const int b = (bg << 4) + row;
        const u32* p = (const u32*)hout + ((size_t)b * S_ + t_pr) * 256 + (dir << 7) + (g << 2);
        union { u32 wq[4]; f16x8 v; } u;
#pragma unroll
        for (int j = 0; j < 4; ++j)
          u.wq[j] = __hip_atomic_load(p + j, __ATOMIC_RELAXED, __HIP_MEMORY_SCOPE_AGENT);
        *(f16x8*)&h_s[(row << 8) + ((g ^ (row & 7)) << 3)] = u.v;
      }
    }
    __syncthreads();                               // A: h_s staged

    f32x4 acc0 = accx0, acc1 = accx1;
    if (s > 0) {
      f32x4 aL0 = {}, aL1 = {};
#pragma unroll
      for (int kt = 0; kt < 8; ++kt) {
        const int g = ((kt << 2) + l4) ^ (l15 & 7);
        const f16x8 a = *(const f16x8*)&h_s[(l15 << 8) + (g << 3)];
        acc0 = __builtin_amdgcn_mfma_f32_16x16x32_f16(a, bhhH[0][kt], acc0, 0, 0, 0);
        acc1 = __builtin_amdgcn_mfma_f32_16x16x32_f16(a, bhhH[1][kt], acc1, 0, 0, 0);
        aL0 = __builtin_amdgcn_mfma_f32_16x16x32_f16(a, bhhL[0][kt], aL0, 0, 0, 0);
        aL1 = __builtin_amdgcn_mfma_f32_16x16x32_f16(a, bhhL[1][kt], aL1, 0, 0, 0);
      }
      acc0 += aL0 * (1.f / 1024.f);
      acc1 += aL1 * (1.f / 1024.f);
    }

    // ---- gate preacts -> LDS. D frag: row=(l>>4)*4+r, col=l&15 ----
#pragma unroll
    for (int r = 0; r < 4; ++r) {
      const int row = (l4 << 2) + r;
      gates_s[((w << 4) + row) * 33 + l15] = acc0[r];
      gates_s[((w << 4) + row) * 33 + 16 + l15] = acc1[r];
    }
    __syncthreads();                               // gates ready; h_s free

    // ---- cell update: (crow,u0), (crow,u0+1) ----
    {
      float hv[2];
      float css[2] = { cs0, cs1 };
#pragma unroll
      for (int j = 0; j < 2; ++j) {
        const int u = u0 + j;
        const float gi = gates_s[(0 * 16 + crow) * 33 + u] + bv[0][j];
        const float gf = gates_s[(1 * 16 + crow) * 33 + u] + bv[1][j];
        const float gg = gates_s[(2 * 16 + crow) * 33 + u] + bv[2][j];
        const float go = gates_s[(3 * 16 + crow) * 33 + u] + bv[3][j];
        float cc = sigf(gf) * css[j] + sigf(gi) * tanh_f(gg);
        css[j] = cc;
        hv[j] = sigf(go) * tanh_f(cc);
      }
      cs0 = css[0]; cs1 = css[1];
      union { u16 hw[2]; u32 pk; } u;
      u.hw[0] = __builtin_bit_cast(u16, (f16)hv[0]);
      u.hw[1] = __builtin_bit_cast(u16, (f16)hv[1]);
      const int b = (bg << 4) + crow;
      u32* dst = (u32*)hout + ((size_t)b * S_ + t_or) * 256 + (dir << 7) + (sl << 4) + (u0 >> 1);
      __hip_atomic_store(dst, u.pk, __ATOMIC_RELAXED, __HIP_MEMORY_SCOPE_AGENT);
    }

    __threadfence();
    __syncthreads();                               // B: stores fenced; LDS free
    if (tid == 0)
      __hip_atomic_fetch_add(&ctr[grp], 1u, __ATOMIC_RELEASE, __HIP_MEMORY_SCOPE_AGENT);

    if (s + 1 < S_) {
      // ---- overlap: stage + x-MFMAs for step s+1 while h propagates ----
      const int t_nx = dir ? (t_or - 1) : (t_or + 1);
      STAGE_X(t_nx);
      __syncthreads();                             // C: x_s staged
      accx0 = (f32x4){}; accx1 = (f32x4){};
      X_MFMA(accx0, accx1);
      if (tid == 0) {
        const u32 target = 8u * (u32)(s + 1);
        while (__hip_atomic_load(&ctr[grp], __ATOMIC_ACQUIRE, __HIP_MEMORY_SCOPE_AGENT) < target)
          __builtin_amdgcn_s_sleep(2);
      }
      __syncthreads();                             // D: h(s) ready everywhere
    }
  }
#undef STAGE_X
#undef X_MFMA
}

// ---------------------------------------------------------------------------
__global__ __launch_bounds__(256) void fc_head(
    const f16* __restrict__ hbuf,    // [B][S][512]
    const float* __restrict__ fc1_w, const float* __restrict__ fc1_b,
    const float* __restrict__ fc2_w, const float* __restrict__ fc2_b,
    const float* __restrict__ fc3_w, const float* __restrict__ fc3_b,
    float* __restrict__ out)
{
  __shared__ float last[512];
  __shared__ float h1[256];
  __shared__ float h2[128];
  const int b = blockIdx.x;
  const int t = threadIdx.x;
  for (int i = t; i < 512; i += 256)
    last[i] = (float)hbuf[((size_t)b * S_ + (S_ - 1)) * 512 + i];
  __syncthreads();
  {
    float a = fc1_b[t];
    for (int k = 0; k < 512; ++k) a = fmaf(last[k], fc1_w[t * 512 + k], a);
    h1[t] = fmaxf(a, 0.f);
  }
  __syncthreads();
  if (t < 128) {
    float a = fc2_b[t];
    for (int k = 0; k < 256; ++k) a = fmaf(h1[k], fc2_w[t * 256 + k], a);
    h2[t] = fmaxf(a, 0.f);
  }
  __syncthreads();
  if (t == 0) {
    float a = fc3_b[0];
    for (int k = 0; k < 128; ++k) a = fmaf(h2[k], fc3_w[k], a);
    out[b] = a;
  }
}

__global__ void zero_ctrs(u32* c, int n) {
  const int i = blockIdx.x * blockDim.x + threadIdx.x;
  if (i < n) c[i] = 0u;
}

__global__ void sentinel(float* out, int n, float v) {
  const int i = blockIdx.x * blockDim.x + threadIdx.x;
  if (i < n) out[i] = v;
}

// ---------------------------------------------------------------------------
extern "C" void kernel_launch(void* const* d_in, const int* in_sizes, int n_in,
                              void* d_out, int out_size, void* d_ws, size_t ws_size,
                              hipStream_t stream) {
  (void)in_sizes; (void)n_in;
  const float* x      = (const float*)d_in[0];
  const float* w_ih0  = (const float*)d_in[1];
  const float* w_hh0  = (const float*)d_in[2];
  const float* b0     = (const float*)d_in[3];
  const float* w_ih_r = (const float*)d_in[4];
  const float* w_hh_r = (const float*)d_in[5];
  const float* b_r    = (const float*)d_in[6];
  const float* fc1_w  = (const float*)d_in[7];
  const float* fc1_b  = (const float*)d_in[8];
  const float* fc2_w  = (const float*)d_in[9];
  const float* fc2_b  = (const float*)d_in[10];
  const float* fc3_w  = (const float*)d_in[11];
  const float* fc3_b  = (const float*)d_in[12];
  float* out = (float*)d_out;

  const size_t hbuf_bytes = (size_t)B_ * S_ * 512 * 2;      // 128 MiB
  if (ws_size < 2 * hbuf_bytes) {
    sentinel<<<1, 256, 0, stream>>>(out, out_size, (float)(ws_size >> 20));
    return;
  }
  f16* hA = (f16*)d_ws;
  f16* hB = (f16*)((char*)d_ws + hbuf_bytes);
  u32* ctrs = (u32*)d_out;   // 96 u32 of the output buffer; overwritten by
                             // fc_head at the end; re-zeroed every launch.

  zero_ctrs<<<1, 96, 0, stream>>>(ctrs, 96);

  // layer 0: x (fp32, K=64) -> hA
  lstm_layer<float, 64><<<256, 256, 0, stream>>>(x, w_ih0, w_hh0, b0, hA, ctrs + 0);
  // layer 1: hA -> hB
  lstm_layer<f16, 512><<<256, 256, 0, stream>>>(hA, w_ih_r, w_hh_r, b_r, hB, ctrs + 32);
  // layer 2: hB -> hA
  lstm_layer<f16, 512><<<256, 256, 0, stream>>>(
      hB, w_ih_r + (size_t)2 * 1024 * 512, w_hh_r + (size_t)2 * 1024 * 256,
      b_r + 2048, hA, ctrs + 64);

  fc_head<<<B_, 256, 0, stream>>>(hA, fc1_w, fc1_b, fc2_w, fc2_b, fc3_w, fc3_b, out);
}

// Round 6
// 8413.330 us; speedup vs baseline: 4.9323x; 4.9323x over previous
//
#include <hip/hip_runtime.h>
#include <cstdint>
#include <cstddef>

#define B_ 256
#define S_ 512

typedef _Float16 f16;
typedef _Float16 f16x8 __attribute__((ext_vector_type(8)));
typedef float f32x4 __attribute__((ext_vector_type(4)));
using u32 = unsigned int;
using u16 = unsigned short;

__device__ __forceinline__ float sigf(float x) { return 1.f / (1.f + __expf(-x)); }
__device__ __forceinline__ float tanh_f(float x) {
  x = fminf(15.f, fmaxf(-15.f, x));
  const float e = __expf(-2.f * x);
  return (1.f - e) / (1.f + e);
}
__device__ __forceinline__ f16x8 cvt_f16x8(float4 a, float4 b) {
  f16x8 t;
  t[0] = (f16)a.x; t[1] = (f16)a.y; t[2] = (f16)a.z; t[3] = (f16)a.w;
  t[4] = (f16)b.x; t[5] = (f16)b.y; t[6] = (f16)b.z; t[7] = (f16)b.w;
  return t;
}

// ---------------------------------------------------------------------------
// Persistent fused BiLSTM layer, ONE plain launch per layer (256 wgs = 1/CU).
// logical wg = dir*128 + bg*8 + sl : 16 batch rows x 128 gate cols.
// W_ih (f16) and W_hh (f16 hi + f16 lo*2^10) slices live in registers.
// gates = x@Wih^T + h@WhhHi^T + (h@WhhLo^T)/1024 + b  via mfma 16x16x32 f16.
// h exchanged through hout with RELAXED agent-scope atomics (sc1 coherence
// routing, NO cache-maintenance ops) + per-(dir,bg) 8-wg counter barrier.
// Store->post ordering via explicit per-thread s_waitcnt vmcnt(0) + barrier.
// x-MFMAs for step s+1 issue BETWEEN ctr-post and spin (latency overlap).
// ---------------------------------------------------------------------------
template<typename TIN, int KIN>
__global__ __launch_bounds__(256, 1) void lstm_layer(
    const TIN* __restrict__ xin,    // [B][S][KIN]  (x fp32 or prev hbuf f16)
    const float* __restrict__ w_ih, // [2][1024][KIN]
    const float* __restrict__ w_hh, // [2][1024][256]
    const float* __restrict__ bias, // [2][1024]
    f16* __restrict__ hout,         // [B][S][512]
    u32* __restrict__ ctr)          // [32] zeroed counters for this layer
{
  constexpr int GPR = KIN / 8;                  // 8-f16 granules per input row
  __shared__ __align__(16) f16 x_s[16 * KIN];
  __shared__ __align__(16) f16 h_s[16 * 256];
  __shared__ float gates_s[64 * 33];

  const int tid = threadIdx.x;
  const int lane = tid & 63, w = tid >> 6;
  const int l15 = lane & 15, l4 = lane >> 4;
  const int phys = blockIdx.x;
  const int wg = ((phys & 7) << 5) | (phys >> 3);  // co-locate groups per XCD
  const int dir = wg >> 7, bg = (wg >> 3) & 15, sl = wg & 7;
  const int grp = (dir << 4) | bg;

  // ---- weight slices -> registers ----
  f16x8 bih[2][KIN / 32];
  f16x8 bhhH[2][8], bhhL[2][8];
#pragma unroll
  for (int nt = 0; nt < 2; ++nt) {
    const int grow = (w << 8) + (sl << 5) + (nt << 4) + l15;   // gate col
    const float* pih = w_ih + ((size_t)(dir << 10) + grow) * KIN + (l4 << 3);
#pragma unroll
    for (int kt = 0; kt < KIN / 32; ++kt) {
      const float* p = pih + (kt << 5);
      bih[nt][kt] = cvt_f16x8(*(const float4*)p, *(const float4*)(p + 4));
    }
    const float* phh = w_hh + ((size_t)(dir << 10) + grow) * 256 + (l4 << 3);
#pragma unroll
    for (int kt = 0; kt < 8; ++kt) {
      const float* p = phh + (kt << 5);
      float wf[8];
      *(float4*)&wf[0] = *(const float4*)p;
      *(float4*)&wf[4] = *(const float4*)(p + 4);
      f16x8 hi, lo;
#pragma unroll
      for (int j = 0; j < 8; ++j) {
        hi[j] = (f16)wf[j];
        lo[j] = (f16)((wf[j] - (float)hi[j]) * 1024.f);
      }
      bhhH[nt][kt] = hi;
      bhhL[nt][kt] = lo;
    }
  }

  // ---- per-thread cell constants ----
  const int crow = tid >> 4;
  const int u0 = (tid & 15) << 1;
  float bv[4][2];
#pragma unroll
  for (int g = 0; g < 4; ++g)
#pragma unroll
    for (int j = 0; j < 2; ++j)
      bv[g][j] = bias[(dir << 10) + (g << 8) + (sl << 5) + u0 + j];
  float cs0 = 0.f, cs1 = 0.f;

  // ---------- staging helpers (inline blocks) ----------
#define STAGE_X(T_OR)                                                          \
  {                                                                            \
    constexpr int NG = 16 * GPR;                                               \
    _Pragma("unroll")                                                          \
    for (int i = 0; i < (NG + 255) / 256; ++i) {                               \
      const int G = tid + (i << 8);                                            \
      if (NG < 256 && G >= NG) break;                                          \
      const int row = G / GPR, g = G % GPR;                                    \
      const int b = (bg << 4) + row;                                           \
      f16x8 v;                                                                 \
      if constexpr (sizeof(TIN) == 4) {                                        \
        const float* p = (const float*)xin + ((size_t)b * S_ + (T_OR)) * KIN + (g << 3); \
        v = cvt_f16x8(*(const float4*)p, *(const float4*)(p + 4));             \
      } else {                                                                 \
        v = *(const f16x8*)((const f16*)xin + ((size_t)b * S_ + (T_OR)) * KIN + (g << 3)); \
      }                                                                        \
      *(f16x8*)&x_s[row * KIN + ((g ^ (row & 7)) << 3)] = v;                   \
    }                                                                          \
  }

#define X_MFMA(A0, A1)                                                         \
  {                                                                            \
    _Pragma("unroll")                                                          \
    for (int kt = 0; kt < KIN / 32; ++kt) {                                    \
      const int g = ((kt << 2) + l4) ^ (l15 & 7);                              \
      const f16x8 a = *(const f16x8*)&x_s[l15 * KIN + (g << 3)];               \
      A0 = __builtin_amdgcn_mfma_f32_16x16x32_f16(a, bih[0][kt], A0, 0, 0, 0); \
      A1 = __builtin_amdgcn_mfma_f32_16x16x32_f16(a, bih[1][kt], A1, 0, 0, 0); \
    }                                                                          \
  }

  // ---- prologue: stage x(0), compute its x-part ----
  const int t_or0 = dir ? (S_ - 1) : 0;
  STAGE_X(t_or0);
  __syncthreads();
  f32x4 accx0 = {}, accx1 = {};
  X_MFMA(accx0, accx1);

  for (int s = 0; s < S_; ++s) {
    const int t_or = dir ? (S_ - 1 - s) : s;

    // ---- stage h(s-1) (ready per barrier) ----
    if (s > 0) {
      const int t_pr = dir ? (t_or + 1) : (t_or - 1);
#pragma unroll
      for (int i = 0; i < 2; ++i) {
        const int G = tid + (i << 8);
        const int row = G >> 5, g = G & 31;
        const int b = (bg << 4) + row;
        const u32* p = (const u32*)hout + ((size_t)b * S_ + t_pr) * 256 + (dir << 7) + (g << 2);
        union { u32 wq[4]; f16x8 v; } u;
#pragma unroll
        for (int j = 0; j < 4; ++j)
          u.wq[j] = __hip_atomic_load(p + j, __ATOMIC_RELAXED, __HIP_MEMORY_SCOPE_AGENT);
        *(f16x8*)&h_s[(row << 8) + ((g ^ (row & 7)) << 3)] = u.v;
      }
    }
    __syncthreads();                               // A: h_s staged

    f32x4 acc0 = accx0, acc1 = accx1;
    if (s > 0) {
      f32x4 aL0 = {}, aL1 = {};
#pragma unroll
      for (int kt = 0; kt < 8; ++kt) {
        const int g = ((kt << 2) + l4) ^ (l15 & 7);
        const f16x8 a = *(const f16x8*)&h_s[(l15 << 8) + (g << 3)];
        acc0 = __builtin_amdgcn_mfma_f32_16x16x32_f16(a, bhhH[0][kt], acc0, 0, 0, 0);
        acc1 = __builtin_amdgcn_mfma_f32_16x16x32_f16(a, bhhH[1][kt], acc1, 0, 0, 0);
        aL0 = __builtin_amdgcn_mfma_f32_16x16x32_f16(a, bhhL[0][kt], aL0, 0, 0, 0);
        aL1 = __builtin_amdgcn_mfma_f32_16x16x32_f16(a, bhhL[1][kt], aL1, 0, 0, 0);
      }
      acc0 += aL0 * (1.f / 1024.f);
      acc1 += aL1 * (1.f / 1024.f);
    }

    // ---- gate preacts -> LDS. D frag: row=(l>>4)*4+r, col=l&15 ----
#pragma unroll
    for (int r = 0; r < 4; ++r) {
      const int row = (l4 << 2) + r;
      gates_s[((w << 4) + row) * 33 + l15] = acc0[r];
      gates_s[((w << 4) + row) * 33 + 16 + l15] = acc1[r];
    }
    __syncthreads();                               // gates ready; h_s free

    // ---- cell update: (crow,u0), (crow,u0+1) ----
    {
      float hv[2];
      float css[2] = { cs0, cs1 };
#pragma unroll
      for (int j = 0; j < 2; ++j) {
        const int u = u0 + j;
        const float gi = gates_s[(0 * 16 + crow) * 33 + u] + bv[0][j];
        const float gf = gates_s[(1 * 16 + crow) * 33 + u] + bv[1][j];
        const float gg = gates_s[(2 * 16 + crow) * 33 + u] + bv[2][j];
        const float go = gates_s[(3 * 16 + crow) * 33 + u] + bv[3][j];
        float cc = sigf(gf) * css[j] + sigf(gi) * tanh_f(gg);
        css[j] = cc;
        hv[j] = sigf(go) * tanh_f(cc);
      }
      cs0 = css[0]; cs1 = css[1];
      union { u16 hw[2]; u32 pk; } u;
      u.hw[0] = __builtin_bit_cast(u16, (f16)hv[0]);
      u.hw[1] = __builtin_bit_cast(u16, (f16)hv[1]);
      const int b = (bg << 4) + crow;
      u32* dst = (u32*)hout + ((size_t)b * S_ + t_or) * 256 + (dir << 7) + (sl << 4) + (u0 >> 1);
      __hip_atomic_store(dst, u.pk, __ATOMIC_RELAXED, __HIP_MEMORY_SCOPE_AGENT);
    }

    // ---- ack own h-stores (sc1 -> coherence point), then group barrier ----
    asm volatile("s_waitcnt vmcnt(0)" ::: "memory");
    __syncthreads();                               // B: all stores acked
    if (tid == 0)
      __hip_atomic_fetch_add(&ctr[grp], 1u, __ATOMIC_RELAXED, __HIP_MEMORY_SCOPE_AGENT);

    if (s + 1 < S_) {
      // ---- overlap: stage + x-MFMAs for step s+1 while h propagates ----
      const int t_nx = dir ? (t_or - 1) : (t_or + 1);
      STAGE_X(t_nx);
      __syncthreads();                             // C: x_s staged
      accx0 = (f32x4){}; accx1 = (f32x4){};
      X_MFMA(accx0, accx1);
      if (tid == 0) {
        const u32 target = 8u * (u32)(s + 1);
        while (__hip_atomic_load(&ctr[grp], __ATOMIC_RELAXED, __HIP_MEMORY_SCOPE_AGENT) < target)
          __builtin_amdgcn_s_sleep(2);
      }
      __syncthreads();                             // D: h(s) ready everywhere
    }
  }
#undef STAGE_X
#undef X_MFMA
}

// ---------------------------------------------------------------------------
__global__ __launch_bounds__(256) void fc_head(
    const f16* __restrict__ hbuf,    // [B][S][512]
    const float* __restrict__ fc1_w, const float* __restrict__ fc1_b,
    const float* __restrict__ fc2_w, const float* __restrict__ fc2_b,
    const float* __restrict__ fc3_w, const float* __restrict__ fc3_b,
    float* __restrict__ out)
{
  __shared__ float last[512];
  __shared__ float h1[256];
  __shared__ float h2[128];
  const int b = blockIdx.x;
  const int t = threadIdx.x;
  for (int i = t; i < 512; i += 256)
    last[i] = (float)hbuf[((size_t)b * S_ + (S_ - 1)) * 512 + i];
  __syncthreads();
  {
    float a = fc1_b[t];
    for (int k = 0; k < 512; ++k) a = fmaf(last[k], fc1_w[t * 512 + k], a);
    h1[t] = fmaxf(a, 0.f);
  }
  __syncthreads();
  if (t < 128) {
    float a = fc2_b[t];
    for (int k = 0; k < 256; ++k) a = fmaf(h1[k], fc2_w[t * 256 + k], a);
    h2[t] = fmaxf(a, 0.f);
  }
  __syncthreads();
  if (t == 0) {
    float a = fc3_b[0];
    for (int k = 0; k < 128; ++k) a = fmaf(h2[k], fc3_w[k], a);
    out[b] = a;
  }
}

__global__ void zero_ctrs(u32* c, int n) {
  const int i = blockIdx.x * blockDim.x + threadIdx.x;
  if (i < n) c[i] = 0u;
}

__global__ void sentinel(float* out, int n, float v) {
  const int i = blockIdx.x * blockDim.x + threadIdx.x;
  if (i < n) out[i] = v;
}

// ---------------------------------------------------------------------------
extern "C" void kernel_launch(void* const* d_in, const int* in_sizes, int n_in,
                              void* d_out, int out_size, void* d_ws, size_t ws_size,
                              hipStream_t stream) {
  (void)in_sizes; (void)n_in;
  const float* x      = (const float*)d_in[0];
  const float* w_ih0  = (const float*)d_in[1];
  const float* w_hh0  = (const float*)d_in[2];
  const float* b0     = (const float*)d_in[3];
  const float* w_ih_r = (const float*)d_in[4];
  const float* w_hh_r = (const float*)d_in[5];
  const float* b_r    = (const float*)d_in[6];
  const float* fc1_w  = (const float*)d_in[7];
  const float* fc1_b  = (const float*)d_in[8];
  const float* fc2_w  = (const float*)d_in[9];
  const float* fc2_b  = (const float*)d_in[10];
  const float* fc3_w  = (const float*)d_in[11];
  const float* fc3_b  = (const float*)d_in[12];
  float* out = (float*)d_out;

  const size_t hbuf_bytes = (size_t)B_ * S_ * 512 * 2;      // 128 MiB
  if (ws_size < 2 * hbuf_bytes) {
    sentinel<<<1, 256, 0, stream>>>(out, out_size, (float)(ws_size >> 20));
    return;
  }
  f16* hA = (f16*)d_ws;
  f16* hB = (f16*)((char*)d_ws + hbuf_bytes);
  u32* ctrs = (u32*)d_out;   // 96 u32 of the output buffer; overwritten by
                             // fc_head at the end; re-zeroed every launch.

  zero_ctrs<<<1, 96, 0, stream>>>(ctrs, 96);

  // layer 0: x (fp32, K=64) -> hA
  lstm_layer<float, 64><<<256, 256, 0, stream>>>(x, w_ih0, w_hh0, b0, hA, ctrs + 0);
  // layer 1: hA -> hB
  lstm_layer<f16, 512><<<256, 256, 0, stream>>>(hA, w_ih_r, w_hh_r, b_r, hB, ctrs + 32);
  // layer 2: hB -> hA
  lstm_layer<f16, 512><<<256, 256, 0, stream>>>(
      hB, w_ih_r + (size_t)2 * 1024 * 512, w_hh_r + (size_t)2 * 1024 * 256,
      b_r + 2048, hA, ctrs + 64);

  fc_head<<<B_, 256, 0, stream>>>(hA, fc1_w, fc1_b, fc2_w, fc2_b, fc3_w, fc3_b, out);
}

// Round 7
// 3835.259 us; speedup vs baseline: 10.8198x; 2.1937x over previous
//
#include <hip/hip_runtime.h>
#include <cstdint>
#include <cstddef>

#define B_ 256
#define S_ 512

typedef _Float16 f16;
typedef _Float16 f16x8 __attribute__((ext_vector_type(8)));
typedef _Float16 f16x4 __attribute__((ext_vector_type(4)));
typedef float f32x4 __attribute__((ext_vector_type(4)));
using u32 = unsigned int;
using u16 = unsigned short;
using u64 = unsigned long long;

#define TAGX   0x555u
#define MAGIC_ 0x13579BDFu

__device__ __forceinline__ float sigf(float x) { return 1.f / (1.f + __expf(-x)); }
__device__ __forceinline__ float tanh_f(float x) {
  x = fminf(15.f, fmaxf(-15.f, x));
  const float e = __expf(-2.f * x);
  return (1.f - e) / (1.f + e);
}
__device__ __forceinline__ f16x8 cvt_f16x8(float4 a, float4 b) {
  f16x8 t;
  t[0] = (f16)a.x; t[1] = (f16)a.y; t[2] = (f16)a.z; t[3] = (f16)a.w;
  t[4] = (f16)b.x; t[5] = (f16)b.y; t[6] = (f16)b.z; t[7] = (f16)b.w;
  return t;
}

// ---------------------------------------------------------------------------
// x transpose+convert: x[b][t][64] fp32 -> xT[t][b][64] f16  (t-major slabs)
// ---------------------------------------------------------------------------
__global__ __launch_bounds__(256) void transpose_x(
    const float* __restrict__ x, f16* __restrict__ xT)
{
  const int t = blockIdx.x;
  const int col = threadIdx.x & 63;
  const int r0 = threadIdx.x >> 6;
  for (int it = 0; it < 64; ++it) {
    const int row = (it << 2) + r0;
    xT[((size_t)t * 256 + row) * 64 + col] =
        (f16)x[((size_t)row * S_ + t) * 64 + col];
  }
}

// ---------------------------------------------------------------------------
// Persistent fused BiLSTM layer (plain launch, 256 wgs = 1/CU via LDS pad).
// wg = dir*128 + bg*8 + sl : 16 batch rows x 32 h-units (128 gate cols).
// Weights in registers (W_ih f16; W_hh hi/lo split). Exchange of h between
// the 8 wgs of a (dir,bg) group goes through a tagged-f32 parity-double-
// buffered exch ring: tag in low 11 mantissa bits self-validates freshness
// (single round trip, no flags, no fences). hA/aux/l2out use PLAIN stores
// (read-before-overwrite proven by the exch handshake; cross-launch
// visibility via kernel boundaries).
//   L=0: reads xT (K=64), writes hA[t][b][512].
//   L=1: reads hA, writes aux (s<256) / hA in-place (s>=256); one-time
//        fwd<->bwd crossover handshake at s==256 via xprog MAGIC words.
//   L=2: reads {hA,aux} composite, writes only the t=511 slab to l2out.
// ---------------------------------------------------------------------------
template<int L, int KIN>
__global__ __launch_bounds__(256, 1) void lstm_layer(
    const f16* __restrict__ xT,     // [512][256][64]   (L0 input)
    f16* __restrict__ hA,           // [512][256][512]
    f16* __restrict__ aux,          // [2][256][256][256]
    f16* __restrict__ l2out,        // [256][512]
    u64* __restrict__ exch,         // [2 par][2 dir][256 b][128] (u64 = 2 units)
    u32* __restrict__ xprog,        // [2][16][8]
    const float* __restrict__ w_ih, // [2][1024][KIN]
    const float* __restrict__ w_hh, // [2][1024][256]
    const float* __restrict__ bias) // [2][1024]
{
  constexpr int GPR = KIN / 8;              // 16B granules per input row
  constexpr int LG  = (KIN == 512) ? 6 : 3; // log2(GPR)
  constexpr int NG  = 16 * GPR;
  constexpr int XI  = (NG + 255) / 256;     // granules per thread
  __shared__ __align__(16) f16 x_s[16 * KIN];
  __shared__ __align__(16) f16 h_s[16 * 256];
  __shared__ float gates_s[64 * 33];
  __shared__ char pad_[81920];              // force 1 wg/CU

  const int tid = threadIdx.x;
  const int lane = tid & 63, w = tid >> 6;
  const int l15 = lane & 15, l4 = lane >> 4;
  const int phys = blockIdx.x;
  const int wg = ((phys & 7) << 5) | (phys >> 3);  // co-locate groups per XCD
  const int dirv = wg >> 7, bg = (wg >> 3) & 15, sl = wg & 7;
  if ((int)blockIdx.x == -1) { pad_[tid] = 0; }    // keep pad alive

  // ---- weight slices -> registers ----
  f16x8 bih[2][KIN / 32];
  f16x8 bhhH[2][8], bhhL[2][8];
#pragma unroll
  for (int nt = 0; nt < 2; ++nt) {
    const int grow = (w << 8) + (sl << 5) + (nt << 4) + l15;   // gate col
    const float* pih = w_ih + ((size_t)(dirv << 10) + grow) * KIN + (l4 << 3);
#pragma unroll
    for (int kt = 0; kt < KIN / 32; ++kt) {
      const float* p = pih + (kt << 5);
      bih[nt][kt] = cvt_f16x8(*(const float4*)p, *(const float4*)(p + 4));
    }
    const float* phh = w_hh + ((size_t)(dirv << 10) + grow) * 256 + (l4 << 3);
#pragma unroll
    for (int kt = 0; kt < 8; ++kt) {
      const float* p = phh + (kt << 5);
      float wf[8];
      *(float4*)&wf[0] = *(const float4*)p;
      *(float4*)&wf[4] = *(const float4*)(p + 4);
      f16x8 hi, lo;
#pragma unroll
      for (int j = 0; j < 8; ++j) {
        hi[j] = (f16)wf[j];
        lo[j] = (f16)((wf[j] - (float)hi[j]) * 1024.f);
      }
      bhhH[nt][kt] = hi;
      bhhL[nt][kt] = lo;
    }
  }

  // ---- per-thread cell constants ----
  const int crow = tid >> 4;
  const int u0 = (tid & 15) << 1;
  float bv[4][2];
#pragma unroll
  for (int g = 0; g < 4; ++g)
#pragma unroll
    for (int j = 0; j < 2; ++j)
      bv[g][j] = bias[(dirv << 10) + (g << 8) + (sl << 5) + u0 + j];
  float cs0 = 0.f, cs1 = 0.f;

  // ---- input-source address function ----
  auto xsrc = [&](int t, int b, int g) -> const f16* {
    if constexpr (L == 0) {
      return xT + ((size_t)t * 256 + b) * 64 + (g << 3);
    } else if constexpr (L == 1) {
      return hA + ((size_t)t * 256 + b) * 512 + (g << 3);
    } else {
      const int c0 = g << 3;
      if (c0 < 256)
        return (t < 256) ? aux + ((size_t)t * 256 + b) * 256 + c0
                         : hA + ((size_t)t * 256 + b) * 512 + c0;
      const int u = c0 - 256;
      return (t >= 256) ? aux + ((size_t)(256 + (511 - t)) * 256 + b) * 256 + u
                        : hA + ((size_t)t * 256 + b) * 512 + 256 + u;
    }
  };

#define X_MFMA(A0, A1)                                                         \
  {                                                                            \
    _Pragma("unroll")                                                          \
    for (int kt = 0; kt < KIN / 32; ++kt) {                                    \
      const int gg = ((kt << 2) + l4) ^ (l15 & 7);                             \
      const f16x8 a = *(const f16x8*)&x_s[l15 * KIN + (gg << 3)];              \
      A0 = __builtin_amdgcn_mfma_f32_16x16x32_f16(a, bih[0][kt], A0, 0, 0, 0); \
      A1 = __builtin_amdgcn_mfma_f32_16x16x32_f16(a, bih[1][kt], A1, 0, 0, 0); \
    }                                                                          \
  }

  // ---- prologue: stage x(0), compute its x-part ----
  f16x8 xreg[XI];
  {
    const int t0 = dirv ? (S_ - 1) : 0;
#pragma unroll
    for (int i = 0; i < XI; ++i) {
      const int G = tid + (i << 8);
      if (NG < 256 && G >= NG) break;
      const int row = G >> LG, g = G & (GPR - 1);
      xreg[i] = *(const f16x8*)xsrc(t0, (bg << 4) + row, g);
    }
#pragma unroll
    for (int i = 0; i < XI; ++i) {
      const int G = tid + (i << 8);
      if (NG < 256 && G >= NG) break;
      const int row = G >> LG, g = G & (GPR - 1);
      *(f16x8*)&x_s[row * KIN + ((g ^ (row & 7)) << 3)] = xreg[i];
    }
  }
  __syncthreads();
  f32x4 accx0 = {}, accx1 = {};
  X_MFMA(accx0, accx1);

  for (int s = 0; s < S_; ++s) {
    const int t_or = dirv ? (S_ - 1 - s) : s;
    const bool pf = (s + 1 < S_);

    // ---- issue x prefetch for step s+1 (independent of h) ----
    if (pf) {
      const int t_nx = dirv ? (t_or - 1) : (t_or + 1);
#pragma unroll
      for (int i = 0; i < XI; ++i) {
        const int G = tid + (i << 8);
        if (NG < 256 && G >= NG) break;
        const int row = G >> LG, g = G & (GPR - 1);
        xreg[i] = *(const f16x8*)xsrc(t_nx, (bg << 4) + row, g);
      }
    }

    // ---- L1 crossover gate: before first in-place write (s==256) ----
    if constexpr (L == 1) {
      if (s == 256) {
        if (tid < 128) {
          const u32* pw = xprog + (1 - dirv) * 128 + tid;
          while (__hip_atomic_load(pw, __ATOMIC_RELAXED, __HIP_MEMORY_SCOPE_AGENT) != MAGIC_)
            __builtin_amdgcn_s_sleep(2);
        }
        __syncthreads();
      }
    }

    // ---- stage h(s-1) via tagged exch (spin until all 16 tags fresh) ----
    if (s > 0) {
      const u32 tagp = ((u32)(L * 512 + s - 1) ^ TAGX) & 0x7FFu;
      const u64* ex = exch + ((size_t)(((s - 1) & 1) * 2 + dirv)) * 256 * 128;
      u32 vv[4][4];
      for (;;) {
        bool ok = true;
#pragma unroll
        for (int i = 0; i < 4; ++i) {
          const int G = tid + (i << 8);
          const int row = G >> 6, gr = G & 63;
          const int b = (bg << 4) + row;
          const u64* p = ex + b * 128 + (gr << 1);
          const u64 a = __hip_atomic_load(p, __ATOMIC_RELAXED, __HIP_MEMORY_SCOPE_AGENT);
          const u64 c = __hip_atomic_load(p + 1, __ATOMIC_RELAXED, __HIP_MEMORY_SCOPE_AGENT);
          vv[i][0] = (u32)a; vv[i][1] = (u32)(a >> 32);
          vv[i][2] = (u32)c; vv[i][3] = (u32)(c >> 32);
#pragma unroll
          for (int j = 0; j < 4; ++j) ok &= ((vv[i][j] & 0x7FFu) == tagp);
        }
        if (ok) break;
        __builtin_amdgcn_s_sleep(1);
      }
#pragma unroll
      for (int i = 0; i < 4; ++i) {
        const int G = tid + (i << 8);
        const int row = G >> 6, gr = G & 63;
        const int g8 = gr >> 1, half = gr & 1;
        f16x4 hh;
#pragma unroll
        for (int j = 0; j < 4; ++j)
          hh[j] = (f16)__builtin_bit_cast(float, vv[i][j] & 0xFFFFF800u);
        *(f16x4*)&h_s[(row << 8) + ((g8 ^ (row & 7)) << 3) + (half << 2)] = hh;
      }
    }
    __syncthreads();                               // h_s staged

    // ---- MFMAs ----
    f32x4 acc0 = accx0, acc1 = accx1;
    if (s > 0) {
      f32x4 aL0 = {}, aL1 = {};
#pragma unroll
      for (int kt = 0; kt < 8; ++kt) {
        const int gg = ((kt << 2) + l4) ^ (l15 & 7);
        const f16x8 a = *(const f16x8*)&h_s[(l15 << 8) + (gg << 3)];
        acc0 = __builtin_amdgcn_mfma_f32_16x16x32_f16(a, bhhH[0][kt], acc0, 0, 0, 0);
        acc1 = __builtin_amdgcn_mfma_f32_16x16x32_f16(a, bhhH[1][kt], acc1, 0, 0, 0);
        aL0 = __builtin_amdgcn_mfma_f32_16x16x32_f16(a, bhhL[0][kt], aL0, 0, 0, 0);
        aL1 = __builtin_amdgcn_mfma_f32_16x16x32_f16(a, bhhL[1][kt], aL1, 0, 0, 0);
      }
      acc0 += aL0 * (1.f / 1024.f);
      acc1 += aL1 * (1.f / 1024.f);
    }

    // ---- gate preacts -> LDS ----
#pragma unroll
    for (int r = 0; r < 4; ++r) {
      const int row = (l4 << 2) + r;
      gates_s[((w << 4) + row) * 33 + l15] = acc0[r];
      gates_s[((w << 4) + row) * 33 + 16 + l15] = acc1[r];
    }
    __syncthreads();

    // ---- cell update ----
    float hv[2];
    {
      float css[2] = { cs0, cs1 };
#pragma unroll
      for (int j = 0; j < 2; ++j) {
        const int u = u0 + j;
        const float gi = gates_s[(0 * 16 + crow) * 33 + u] + bv[0][j];
        const float gf = gates_s[(1 * 16 + crow) * 33 + u] + bv[1][j];
        const float gg = gates_s[(2 * 16 + crow) * 33 + u] + bv[2][j];
        const float go = gates_s[(3 * 16 + crow) * 33 + u] + bv[3][j];
        float cc = sigf(gf) * css[j] + sigf(gi) * tanh_f(gg);
        css[j] = cc;
        hv[j] = sigf(go) * tanh_f(cc);
      }
      cs0 = css[0]; cs1 = css[1];
    }

    // ---- secure x prefetch, then publish h(s) (tagged exch + hout) ----
    asm volatile("s_waitcnt vmcnt(0)" ::: "memory");
    {
      const u32 tagc = ((u32)(L * 512 + s) ^ TAGX) & 0x7FFu;
      const u32 w0 = ((__builtin_bit_cast(u32, hv[0]) + 0x400u) & 0xFFFFF800u) | tagc;
      const u32 w1 = ((__builtin_bit_cast(u32, hv[1]) + 0x400u) & 0xFFFFF800u) | tagc;
      const u64 pk = (u64)w0 | ((u64)w1 << 32);
      const int b = (bg << 4) + crow;
      __hip_atomic_store(
          exch + ((size_t)((s & 1) * 2 + dirv)) * 256 * 128 + b * 128 + (sl << 4) + (u0 >> 1),
          pk, __ATOMIC_RELAXED, __HIP_MEMORY_SCOPE_AGENT);

      union { u16 hw[2]; u32 pkh; } uh;
      uh.hw[0] = __builtin_bit_cast(u16, (f16)hv[0]);
      uh.hw[1] = __builtin_bit_cast(u16, (f16)hv[1]);
      const int uoff = (dirv << 7) + (sl << 4) + (u0 >> 1);
      if constexpr (L == 0) {
        ((u32*)hA)[((size_t)t_or * 256 + b) * 256 + uoff] = uh.pkh;
      } else if constexpr (L == 1) {
        if (s < 256)
          ((u32*)aux)[((size_t)(dirv * 256 + s) * 256 + b) * 128 + (sl << 4) + (u0 >> 1)] = uh.pkh;
        else
          ((u32*)hA)[((size_t)t_or * 256 + b) * 256 + uoff] = uh.pkh;
      } else {
        if (t_or == S_ - 1)
          ((u32*)l2out)[(size_t)b * 256 + uoff] = uh.pkh;
      }
    }

    // ---- L1: publish crossover MAGIC once h(254) is globally posted ----
    if constexpr (L == 1) {
      if (s == 254) {
        asm volatile("s_waitcnt vmcnt(0)" ::: "memory");
        __syncthreads();
        if (tid == 0)
          __hip_atomic_store(xprog + dirv * 128 + (bg << 3) + sl, MAGIC_,
                             __ATOMIC_RELAXED, __HIP_MEMORY_SCOPE_AGENT);
      }
    }

    // ---- write x_s for s+1 and pre-compute its x-part ----
    if (pf) {
#pragma unroll
      for (int i = 0; i < XI; ++i) {
        const int G = tid + (i << 8);
        if (NG < 256 && G >= NG) break;
        const int row = G >> LG, g = G & (GPR - 1);
        *(f16x8*)&x_s[row * KIN + ((g ^ (row & 7)) << 3)] = xreg[i];
      }
      __syncthreads();
      accx0 = (f32x4){}; accx1 = (f32x4){};
      X_MFMA(accx0, accx1);
    }
  }
#undef X_MFMA
}

// ---------------------------------------------------------------------------
__global__ __launch_bounds__(256) void fc_head(
    const f16* __restrict__ l2out,   // [B][512]
    const float* __restrict__ fc1_w, const float* __restrict__ fc1_b,
    const float* __restrict__ fc2_w, const float* __restrict__ fc2_b,
    const float* __restrict__ fc3_w, const float* __restrict__ fc3_b,
    float* __restrict__ out)
{
  __shared__ float last[512];
  __shared__ float h1[256];
  __shared__ float h2[128];
  const int b = blockIdx.x;
  const int t = threadIdx.x;
  for (int i = t; i < 512; i += 256)
    last[i] = (float)l2out[(size_t)b * 512 + i];
  __syncthreads();
  {
    float a = fc1_b[t];
    for (int k = 0; k < 512; ++k) a = fmaf(last[k], fc1_w[t * 512 + k], a);
    h1[t] = fmaxf(a, 0.f);
  }
  __syncthreads();
  if (t < 128) {
    float a = fc2_b[t];
    for (int k = 0; k < 256; ++k) a = fmaf(h1[k], fc2_w[t * 256 + k], a);
    h2[t] = fmaxf(a, 0.f);
  }
  __syncthreads();
  if (t == 0) {
    float a = fc3_b[0];
    for (int k = 0; k < 128; ++k) a = fmaf(h2[k], fc3_w[k], a);
    out[b] = a;
  }
}

__global__ void sentinel(float* out, int n, float v) {
  const int i = blockIdx.x * blockDim.x + threadIdx.x;
  if (i < n) out[i] = v;
}

// ---------------------------------------------------------------------------
extern "C" void kernel_launch(void* const* d_in, const int* in_sizes, int n_in,
                              void* d_out, int out_size, void* d_ws, size_t ws_size,
                              hipStream_t stream) {
  (void)in_sizes; (void)n_in;
  const float* x      = (const float*)d_in[0];
  const float* w_ih0  = (const float*)d_in[1];
  const float* w_hh0  = (const float*)d_in[2];
  const float* b0     = (const float*)d_in[3];
  const float* w_ih_r = (const float*)d_in[4];
  const float* w_hh_r = (const float*)d_in[5];
  const float* b_r    = (const float*)d_in[6];
  const float* fc1_w  = (const float*)d_in[7];
  const float* fc1_b  = (const float*)d_in[8];
  const float* fc2_w  = (const float*)d_in[9];
  const float* fc2_b  = (const float*)d_in[10];
  const float* fc3_w  = (const float*)d_in[11];
  const float* fc3_b  = (const float*)d_in[12];
  float* out = (float*)d_out;

  // ---- workspace carve (bytes) ----
  const size_t off_hA    = 0;                              // 134,217,728
  const size_t off_aux   = off_hA   + (size_t)512*256*512*2;
  const size_t off_xT    = off_aux  + (size_t)2*256*256*256*2;   // +67,108,864
  const size_t off_l2o   = off_xT   + (size_t)512*256*64*2;      // +16,777,216
  const size_t off_exch  = off_l2o  + (size_t)256*512*2;         // +262,144
  const size_t off_xprog = off_exch + (size_t)2*2*256*128*8;     // +1,048,576
  const size_t need      = off_xprog + 1024;
  if (ws_size < need) {
    sentinel<<<1, 256, 0, stream>>>(out, out_size, (float)(ws_size >> 20));
    return;
  }
  char* ws = (char*)d_ws;
  f16* hA    = (f16*)(ws + off_hA);
  f16* aux   = (f16*)(ws + off_aux);
  f16* xT    = (f16*)(ws + off_xT);
  f16* l2out = (f16*)(ws + off_l2o);
  u64* exch  = (u64*)(ws + off_exch);
  u32* xprog = (u32*)(ws + off_xprog);

  // kill stale tags / MAGIC from previous replays (0xAA aliases no (L,s) tag)
  hipMemsetAsync(ws + off_exch, 0xAA, (size_t)2*2*256*128*8 + 1024, stream);

  transpose_x<<<512, 256, 0, stream>>>(x, xT);

  lstm_layer<0, 64><<<256, 256, 0, stream>>>(
      xT, hA, aux, l2out, exch, xprog, w_ih0, w_hh0, b0);
  lstm_layer<1, 512><<<256, 256, 0, stream>>>(
      xT, hA, aux, l2out, exch, xprog, w_ih_r, w_hh_r, b_r);
  lstm_layer<2, 512><<<256, 256, 0, stream>>>(
      xT, hA, aux, l2out, exch, xprog,
      w_ih_r + (size_t)2 * 1024 * 512, w_hh_r + (size_t)2 * 1024 * 256,
      b_r + 2048);

  fc_head<<<B_, 256, 0, stream>>>(l2out, fc1_w, fc1_b, fc2_w, fc2_b, fc3_w, fc3_b, out);
}